// Round 2
// baseline (588.080 us; speedup 1.0000x reference)
//
#include <hip/hip_runtime.h>
#include <stdint.h>

// ReLU relaxation (alpha-CROWN style), N = 8192.
// Output (f32), flat: [conc_low (n)] [conc_up (n)] [A_low (n+1)^2] [A_up (n+1)^2]
// A_low/A_up are diagonal + (A_up) last row; everything else zero.
//
// Timing model (rocprof rounds 0-1): the harness poison (fillBufferAligned,
// ~2.1 GB @ 6.2 TB/s = 345 us) is INSIDE the timed region and is a fixed
// floor. Our controllable cost is one full 537 MB output write. R1's fused
// kernel ran at ~2.7 TB/s — suspect: nontemporal stores bypassing L2
// write-combining. This version uses plain cached stores (the 6.2 TB/s path)
// and amortizes index math over 64 B groups.

typedef float f32x4 __attribute__((ext_vector_type(4)));

struct NodeVals { float diag_low, diag_up, bias_up, conc_low, conc_up; };

__device__ __forceinline__ NodeVals node_vals(float l, float u, float a_raw) {
    NodeVals nv;
    float a = fminf(fmaxf(a_raw, 0.f), 1.f);
    bool active   = (u > 0.f) && (l >= 0.f);
    bool unstable = (u > 0.f) && (l < 0.f);
    float denom = u - l;
    float lam = u / ((denom == 0.f) ? 1.f : denom);
    nv.diag_low = active ? 1.f : (unstable ? a : 0.f);
    nv.diag_up  = active ? 1.f : (unstable ? lam : 0.f);
    nv.bias_up  = unstable ? (-lam * l) : 0.f;
    nv.conc_low = active ? l : (unstable ? (a * l) : 0.f);
    nv.conc_up  = (u > 0.f) ? u : 0.f;
    return nv;
}

template <uint32_t NP1>
__global__ __launch_bounds__(256) void fused_fill(
        const float* __restrict__ lower,
        const float* __restrict__ upper,
        const float* __restrict__ alphas,
        float* __restrict__ out) {
    constexpr uint32_t N     = NP1 - 1;
    constexpr uint32_t NPSQ  = NP1 * NP1;        // 67,125,249 < 2^27
    constexpr uint32_t CONC  = 2 * N;            // 16384
    constexpr uint32_t T     = CONC + 2 * NPSQ;  // 134,266,882 < 2^28
    constexpr uint32_t G     = (T - 2) / 16;     // full 16-element (64 B) groups
    static_assert(N % 16 == 0, "conc region must be group-aligned");
    static_assert(CONC % 16 == 0, "conc region must be group-aligned");
    static_assert(T % 16 == 2, "tail handling assumes 2 trailing elements");

    f32x4* __restrict__ out4 = (f32x4*)out;
    const uint32_t stride = gridDim.x * blockDim.x;

    for (uint32_t j = blockIdx.x * blockDim.x + threadIdx.x; j < G; j += stride) {
        const uint32_t e0 = j * 16u;             // element offset of this group
        f32x4* dst = out4 + (size_t)j * 4;

        if (e0 < CONC) {
            // Dense concrete-bounds region: 1024 groups total, no straddles.
            if (e0 < N) {
                #pragma unroll
                for (int s = 0; s < 4; ++s) {
                    const uint32_t b = e0 + 4u * s;
                    const f32x4 l4 = *(const f32x4*)(lower  + b);
                    const f32x4 u4 = *(const f32x4*)(upper  + b);
                    const f32x4 a4 = *(const f32x4*)(alphas + b);
                    f32x4 v;
                    #pragma unroll
                    for (int k = 0; k < 4; ++k)
                        v[k] = node_vals(l4[k], u4[k], a4[k]).conc_low;
                    dst[s] = v;
                }
            } else {
                #pragma unroll
                for (int s = 0; s < 4; ++s) {
                    const uint32_t b = e0 - N + 4u * s;
                    const f32x4 u4 = *(const f32x4*)(upper + b);
                    f32x4 v;
                    #pragma unroll
                    for (int k = 0; k < 4; ++k)
                        v[k] = (u4[k] > 0.f) ? u4[k] : 0.f;
                    dst[s] = v;
                }
            }
        } else {
            // A_low / A_up region. One magic-div per 64 B group.
            const uint32_t g   = e0 - CONC;             // < 2*NPSQ < 2^28
            const uint32_t mat = (g >= NPSQ) ? 1u : 0u; // 0 = A_low, 1 = A_up
            const uint32_t h   = mat ? (g - NPSQ) : g;
            const uint32_t r   = h / NP1;               // magic-mul (const divisor)
            const uint32_t c   = h - r * NP1;

            // Slow iff the group can contain a nonzero:
            //  - contains the diagonal of this row        (r - c) < 16
            //  - crosses a row boundary (next-row diag / matrix boundary)
            //  - lies in A_up's last (bias) row
            const bool slow = ((r - c) < 16u) |
                              (c > (uint32_t)(NP1 - 16)) |
                              ((mat != 0u) & (r == N));
            if (!slow) {
                const f32x4 z = (f32x4){0.f, 0.f, 0.f, 0.f};
                dst[0] = z; dst[1] = z; dst[2] = z; dst[3] = z;
            } else {
                #pragma unroll
                for (int s = 0; s < 4; ++s) {
                    f32x4 v;
                    #pragma unroll
                    for (int k = 0; k < 4; ++k) {
                        const uint32_t gk = g + 4u * s + k;
                        const uint32_t mk = (gk >= NPSQ) ? 1u : 0u;
                        const uint32_t hk = mk ? (gk - NPSQ) : gk;
                        const uint32_t rk = hk / NP1;
                        const uint32_t ck = hk - rk * NP1;
                        float val = 0.f;
                        if (rk == ck) {
                            if (rk == N) {
                                val = 1.f;                       // A_*[n,n]
                            } else {
                                NodeVals nv = node_vals(lower[rk], upper[rk], alphas[rk]);
                                val = mk ? nv.diag_up : nv.diag_low;
                            }
                        } else if (mk && rk == N) {              // A_up bias row
                            NodeVals nv = node_vals(lower[ck], upper[ck], alphas[ck]);
                            val = nv.bias_up;
                        }
                        v[k] = val;
                    }
                    dst[s] = v;
                }
            }
        }
    }

    // Tail: last 2 elements = A_up[n, n-1] (bias) and A_up[n, n] (= 1).
    if (blockIdx.x == 0 && threadIdx.x == 0) {
        NodeVals nv = node_vals(lower[N - 1], upper[N - 1], alphas[N - 1]);
        out[(size_t)T - 2] = nv.bias_up;
        out[(size_t)T - 1] = 1.f;
    }
}

// Correctness fallback for any n (never taken in the bench; scalar, runtime div).
__global__ void generic_fill(const float* __restrict__ lower,
                             const float* __restrict__ upper,
                             const float* __restrict__ alphas,
                             float* __restrict__ out, int n) {
    const uint32_t np1  = (uint32_t)n + 1;
    const size_t   npsq = (size_t)np1 * np1;
    const size_t   conc = 2 * (size_t)n;
    const size_t   T    = conc + 2 * npsq;
    const size_t stride = (size_t)gridDim.x * blockDim.x;
    for (size_t e = (size_t)blockIdx.x * blockDim.x + threadIdx.x; e < T; e += stride) {
        float val = 0.f;
        if (e < (size_t)n) {
            val = node_vals(lower[e], upper[e], alphas[e]).conc_low;
        } else if (e < conc) {
            size_t i = e - n;
            val = node_vals(lower[i], upper[i], alphas[i]).conc_up;
        } else {
            size_t g = e - conc;
            int mat = (g >= npsq) ? 1 : 0;
            size_t h = mat ? (g - npsq) : g;
            uint32_t r = (uint32_t)(h / np1);
            uint32_t c = (uint32_t)(h - (size_t)r * np1);
            if (r == c) {
                if (r == (uint32_t)n) val = 1.f;
                else {
                    NodeVals nv = node_vals(lower[r], upper[r], alphas[r]);
                    val = mat ? nv.diag_up : nv.diag_low;
                }
            } else if (mat && r == (uint32_t)n) {
                val = node_vals(lower[c], upper[c], alphas[c]).bias_up;
            }
        }
        out[e] = val;
    }
}

extern "C" void kernel_launch(void* const* d_in, const int* in_sizes, int n_in,
                              void* d_out, int out_size, void* d_ws, size_t ws_size,
                              hipStream_t stream) {
    const float* lower  = (const float*)d_in[0];
    const float* upper  = (const float*)d_in[1];
    const float* alphas = (const float*)d_in[2];
    float* out = (float*)d_out;
    const int n = in_sizes[0];

    if (n == 8192) {
        // 8,391,680 64B groups; 2048 blocks x 256 threads = 524,288 threads
        // (exactly full wave residency), 16 groups per thread.
        fused_fill<8193><<<2048, 256, 0, stream>>>(lower, upper, alphas, out);
    } else {
        generic_fill<<<2048, 256, 0, stream>>>(lower, upper, alphas, out, n);
    }
}

// Round 3
// 531.244 us; speedup vs baseline: 1.1070x; 1.1070x over previous
//
#include <hip/hip_runtime.h>
#include <stdint.h>

// ReLU relaxation (alpha-CROWN style), N = 8192.
// Output (f32), flat: [conc_low (n)] [conc_up (n)] [A_low (n+1)^2] [A_up (n+1)^2]
// A_low/A_up are diagonal + (A_up) last row; everything else zero.
//
// Timing model (rocprof r0-r2): harness poison fill (2.148 GB @ 6.2 TB/s =
// 345 us) is inside the timed region and fixed. Controllable cost = one full
// 537 MB output write. Measured: R0 memset+scatter 173 us; R1 fused
// NT/lane-contiguous 212 us (2.5 TB/s); R2 fused cached/thread-blocked 243 us
// (2.2 TB/s). R2 flipped two variables (store mode AND pattern) - the blocked
// pattern breaks per-instruction coalescing (64 lanes x 16B at stride 64B =
// 4KB sparse span vs 1KB contiguous). This round: cached stores WITH the
// lane-contiguous pattern, fixed 32-iteration trip (no per-iter bounds check),
// 4x unroll for store-level parallelism.

typedef float f32x4 __attribute__((ext_vector_type(4)));

struct NodeVals { float diag_low, diag_up, bias_up, conc_low, conc_up; };

__device__ __forceinline__ NodeVals node_vals(float l, float u, float a_raw) {
    NodeVals nv;
    float a = fminf(fmaxf(a_raw, 0.f), 1.f);
    bool active   = (u > 0.f) && (l >= 0.f);
    bool unstable = (u > 0.f) && (l < 0.f);
    float denom = u - l;
    float lam = u / ((denom == 0.f) ? 1.f : denom);
    nv.diag_low = active ? 1.f : (unstable ? a : 0.f);
    nv.diag_up  = active ? 1.f : (unstable ? lam : 0.f);
    nv.bias_up  = unstable ? (-lam * l) : 0.f;
    nv.conc_low = active ? l : (unstable ? (a * l) : 0.f);
    nv.conc_up  = (u > 0.f) ? u : 0.f;
    return nv;
}

template <uint32_t NP1>
__device__ __forceinline__ void process_chunk(uint32_t j,
        const float* __restrict__ lower,
        const float* __restrict__ upper,
        const float* __restrict__ alphas,
        f32x4* __restrict__ out4) {
    constexpr uint32_t N    = NP1 - 1;
    constexpr uint32_t NPSQ = NP1 * NP1;       // 67,125,249 < 2^27
    constexpr uint32_t CONC = 2 * N;           // 16384

    const uint32_t e0 = j * 4u;
    f32x4 v = (f32x4){0.f, 0.f, 0.f, 0.f};

    if (e0 < CONC) {
        // Dense concrete-bounds region (N % 4 == 0: no straddles).
        if (e0 < N) {
            const f32x4 l4 = *(const f32x4*)(lower  + e0);
            const f32x4 u4 = *(const f32x4*)(upper  + e0);
            const f32x4 a4 = *(const f32x4*)(alphas + e0);
            #pragma unroll
            for (int k = 0; k < 4; ++k)
                v[k] = node_vals(l4[k], u4[k], a4[k]).conc_low;
        } else {
            const f32x4 u4 = *(const f32x4*)(upper + (e0 - N));
            #pragma unroll
            for (int k = 0; k < 4; ++k)
                v[k] = (u4[k] > 0.f) ? u4[k] : 0.f;
        }
    } else {
        // A_low / A_up region. One magic-div per 16 B chunk.
        const uint32_t g   = e0 - CONC;
        const uint32_t mat = (g >= NPSQ) ? 1u : 0u;   // 0 = A_low, 1 = A_up
        const uint32_t h   = mat ? (g - NPSQ) : g;
        const uint32_t r   = h / NP1;                 // magic-mul (const divisor)
        const uint32_t c   = h - r * NP1;

        // Slow iff the chunk can contain a nonzero: holds this row's diagonal,
        // wraps a row boundary (next-row diag / matrix boundary), or lies in
        // A_up's last (bias) row.
        const bool slow = ((r - c) <= 3u) |
                          (c > (uint32_t)(NP1 - 4)) |
                          ((mat != 0u) & (r == N));
        if (slow) {
            #pragma unroll
            for (int k = 0; k < 4; ++k) {
                const uint32_t gk = g + (uint32_t)k;
                const uint32_t mk = (gk >= NPSQ) ? 1u : 0u;
                const uint32_t hk = mk ? (gk - NPSQ) : gk;
                const uint32_t rk = hk / NP1;
                const uint32_t ck = hk - rk * NP1;
                float val = 0.f;
                if (rk == ck) {
                    if (rk == N) {
                        val = 1.f;                        // A_*[n,n]
                    } else {
                        NodeVals nv = node_vals(lower[rk], upper[rk], alphas[rk]);
                        val = mk ? nv.diag_up : nv.diag_low;
                    }
                } else if (mk && rk == N) {               // A_up bias row
                    NodeVals nv = node_vals(lower[ck], upper[ck], alphas[ck]);
                    val = nv.bias_up;
                }
                v[k] = val;
            }
        }
    }
    out4[j] = v;   // plain cached store: the demonstrated 6.2 TB/s path
}

template <uint32_t NP1>
__global__ __launch_bounds__(256) void fused_fill(
        const float* __restrict__ lower,
        const float* __restrict__ upper,
        const float* __restrict__ alphas,
        float* __restrict__ out) {
    constexpr uint32_t N       = NP1 - 1;
    constexpr uint32_t NPSQ    = NP1 * NP1;
    constexpr uint32_t CONC    = 2 * N;
    constexpr uint32_t T       = CONC + 2 * NPSQ;    // 134,266,882
    constexpr uint32_t C4      = T / 4;              // 33,566,720 16B chunks
    constexpr uint32_t THREADS = 4096u * 256u;       // 1,048,576
    constexpr uint32_t FULL_IT = C4 / THREADS;       // 32
    constexpr uint32_t TAIL    = C4 - FULL_IT * THREADS;  // 12,288
    static_assert(N % 4 == 0 && T % 4 == 2, "layout assumptions");

    const uint32_t tid = blockIdx.x * blockDim.x + threadIdx.x;
    f32x4* __restrict__ out4 = (f32x4*)out;

    #pragma unroll 4
    for (uint32_t it = 0; it < FULL_IT; ++it)
        process_chunk<NP1>(tid + it * THREADS, lower, upper, alphas, out4);

    if (tid < TAIL)
        process_chunk<NP1>(tid + FULL_IT * THREADS, lower, upper, alphas, out4);

    // Tail: last 2 elements = A_up[n, n-1] (bias) and A_up[n, n] (= 1).
    if (tid == 0) {
        NodeVals nv = node_vals(lower[N - 1], upper[N - 1], alphas[N - 1]);
        out[(size_t)T - 2] = nv.bias_up;
        out[(size_t)T - 1] = 1.f;
    }
}

// Correctness fallback for any n (never taken in the bench; scalar, runtime div).
__global__ void generic_fill(const float* __restrict__ lower,
                             const float* __restrict__ upper,
                             const float* __restrict__ alphas,
                             float* __restrict__ out, int n) {
    const uint32_t np1  = (uint32_t)n + 1;
    const size_t   npsq = (size_t)np1 * np1;
    const size_t   conc = 2 * (size_t)n;
    const size_t   T    = conc + 2 * npsq;
    const size_t stride = (size_t)gridDim.x * blockDim.x;
    for (size_t e = (size_t)blockIdx.x * blockDim.x + threadIdx.x; e < T; e += stride) {
        float val = 0.f;
        if (e < (size_t)n) {
            val = node_vals(lower[e], upper[e], alphas[e]).conc_low;
        } else if (e < conc) {
            size_t i = e - n;
            val = node_vals(lower[i], upper[i], alphas[i]).conc_up;
        } else {
            size_t g = e - conc;
            int mat = (g >= npsq) ? 1 : 0;
            size_t h = mat ? (g - npsq) : g;
            uint32_t r = (uint32_t)(h / np1);
            uint32_t c = (uint32_t)(h - (size_t)r * np1);
            if (r == c) {
                if (r == (uint32_t)n) val = 1.f;
                else {
                    NodeVals nv = node_vals(lower[r], upper[r], alphas[r]);
                    val = mat ? nv.diag_up : nv.diag_low;
                }
            } else if (mat && r == (uint32_t)n) {
                val = node_vals(lower[c], upper[c], alphas[c]).bias_up;
            }
        }
        out[e] = val;
    }
}

extern "C" void kernel_launch(void* const* d_in, const int* in_sizes, int n_in,
                              void* d_out, int out_size, void* d_ws, size_t ws_size,
                              hipStream_t stream) {
    const float* lower  = (const float*)d_in[0];
    const float* upper  = (const float*)d_in[1];
    const float* alphas = (const float*)d_in[2];
    float* out = (float*)d_out;
    const int n = in_sizes[0];

    if (n == 8192) {
        // 4096 blocks x 256 threads = 1,048,576 threads; 32 chunks/thread,
        // lane-contiguous (each wave store = 1 KB contiguous span).
        fused_fill<8193><<<4096, 256, 0, stream>>>(lower, upper, alphas, out);
    } else {
        generic_fill<<<2048, 256, 0, stream>>>(lower, upper, alphas, out, n);
    }
}

// Round 4
// 508.046 us; speedup vs baseline: 1.1575x; 1.0457x over previous
//
#include <hip/hip_runtime.h>
#include <stdint.h>

// ReLU relaxation (alpha-CROWN style), N = 8192.
// Output (f32), flat: [conc_low (n)] [conc_up (n)] [A_low (n+1)^2] [A_up (n+1)^2]
// A_low/A_up are diagonal + (A_up) last row; everything else zero.
//
// Timing model (rocprof r0-r3): harness poison fill (2.148 GB @ 6.2 TB/s =
// 345 us, proving pure-write 6.2 TB/s on this chip) is inside the timed
// region and fixed. Controllable cost = one 537 MB output write.
//   R0 memset+scatter: 173 us   R1 fused NT/loop: 212 us
//   R2 fused cached/blocked: 243 us   R3 fused cached/loop: 186 us (2.9 TB/s)
// Kernel stores run at <1/2 the demonstrated fill rate. The one untested
// structural difference vs fillBufferAligned: the fill is a flat one-shot
// kernel (huge grid, one store per short-lived thread, block-ordered
// monotonic addresses), ours was a persistent 32-iteration loop. This round
// flips ONLY that: flat grid, one 16 B chunk per thread, exact cover.

typedef float f32x4 __attribute__((ext_vector_type(4)));

struct NodeVals { float diag_low, diag_up, bias_up, conc_low, conc_up; };

__device__ __forceinline__ NodeVals node_vals(float l, float u, float a_raw) {
    NodeVals nv;
    float a = fminf(fmaxf(a_raw, 0.f), 1.f);
    bool active   = (u > 0.f) && (l >= 0.f);
    bool unstable = (u > 0.f) && (l < 0.f);
    float denom = u - l;
    float lam = u / ((denom == 0.f) ? 1.f : denom);
    nv.diag_low = active ? 1.f : (unstable ? a : 0.f);
    nv.diag_up  = active ? 1.f : (unstable ? lam : 0.f);
    nv.bias_up  = unstable ? (-lam * l) : 0.f;
    nv.conc_low = active ? l : (unstable ? (a * l) : 0.f);
    nv.conc_up  = (u > 0.f) ? u : 0.f;
    return nv;
}

template <uint32_t NP1>
__global__ __launch_bounds__(256) void fused_fill_flat(
        const float* __restrict__ lower,
        const float* __restrict__ upper,
        const float* __restrict__ alphas,
        float* __restrict__ out) {
    constexpr uint32_t N    = NP1 - 1;
    constexpr uint32_t NPSQ = NP1 * NP1;        // 67,125,249 < 2^27
    constexpr uint32_t CONC = 2 * N;            // 16384
    constexpr uint32_t T    = CONC + 2 * NPSQ;  // 134,266,882
    static_assert(N % 4 == 0 && T % 4 == 2, "layout assumptions");

    const uint32_t j  = blockIdx.x * 256u + threadIdx.x;  // 16B chunk index
    const uint32_t e0 = j * 4u;
    f32x4* __restrict__ out4 = (f32x4*)out;
    f32x4 v = (f32x4){0.f, 0.f, 0.f, 0.f};

    if (e0 < CONC) {
        // Dense concrete-bounds region (N % 4 == 0: no straddles).
        if (e0 < N) {
            const f32x4 l4 = *(const f32x4*)(lower  + e0);
            const f32x4 u4 = *(const f32x4*)(upper  + e0);
            const f32x4 a4 = *(const f32x4*)(alphas + e0);
            #pragma unroll
            for (int k = 0; k < 4; ++k)
                v[k] = node_vals(l4[k], u4[k], a4[k]).conc_low;
        } else {
            const f32x4 u4 = *(const f32x4*)(upper + (e0 - N));
            #pragma unroll
            for (int k = 0; k < 4; ++k)
                v[k] = (u4[k] > 0.f) ? u4[k] : 0.f;
        }
    } else {
        // A_low / A_up region. One magic-div (const divisor) per chunk.
        const uint32_t g   = e0 - CONC;
        const uint32_t mat = (g >= NPSQ) ? 1u : 0u;   // 0 = A_low, 1 = A_up
        const uint32_t h   = mat ? (g - NPSQ) : g;
        const uint32_t r   = h / NP1;
        const uint32_t c   = h - r * NP1;

        // Slow iff the chunk can contain a nonzero: holds this row's diagonal,
        // wraps a row boundary (next-row diag / matrix boundary), or lies in
        // A_up's last (bias) row.
        const bool slow = ((r - c) <= 3u) |
                          (c > (uint32_t)(NP1 - 4)) |
                          ((mat != 0u) & (r == N));
        if (slow) {
            #pragma unroll
            for (int k = 0; k < 4; ++k) {
                const uint32_t gk = g + (uint32_t)k;
                const uint32_t mk = (gk >= NPSQ) ? 1u : 0u;
                const uint32_t hk = mk ? (gk - NPSQ) : gk;
                const uint32_t rk = hk / NP1;
                const uint32_t ck = hk - rk * NP1;
                float val = 0.f;
                if (rk == ck) {
                    if (rk == N) {
                        val = 1.f;                        // A_*[n,n]
                    } else {
                        NodeVals nv = node_vals(lower[rk], upper[rk], alphas[rk]);
                        val = mk ? nv.diag_up : nv.diag_low;
                    }
                } else if (mk && rk == N) {               // A_up bias row
                    NodeVals nv = node_vals(lower[ck], upper[ck], alphas[ck]);
                    val = nv.bias_up;
                }
                v[k] = val;
            }
        }
    }

    out4[j] = v;   // plain cached dwordx4 store, 1 KB contiguous per wave

    // Tail: last 2 elements = A_up[n, n-1] (bias) and A_up[n, n] (= 1).
    if (j == 0) {
        NodeVals nv = node_vals(lower[N - 1], upper[N - 1], alphas[N - 1]);
        out[(size_t)T - 2] = nv.bias_up;
        out[(size_t)T - 1] = 1.f;
    }
}

// Correctness fallback for any n (never taken in the bench; scalar, runtime div).
__global__ void generic_fill(const float* __restrict__ lower,
                             const float* __restrict__ upper,
                             const float* __restrict__ alphas,
                             float* __restrict__ out, int n) {
    const uint32_t np1  = (uint32_t)n + 1;
    const size_t   npsq = (size_t)np1 * np1;
    const size_t   conc = 2 * (size_t)n;
    const size_t   T    = conc + 2 * npsq;
    const size_t stride = (size_t)gridDim.x * blockDim.x;
    for (size_t e = (size_t)blockIdx.x * blockDim.x + threadIdx.x; e < T; e += stride) {
        float val = 0.f;
        if (e < (size_t)n) {
            val = node_vals(lower[e], upper[e], alphas[e]).conc_low;
        } else if (e < conc) {
            size_t i = e - n;
            val = node_vals(lower[i], upper[i], alphas[i]).conc_up;
        } else {
            size_t g = e - conc;
            int mat = (g >= npsq) ? 1 : 0;
            size_t h = mat ? (g - npsq) : g;
            uint32_t r = (uint32_t)(h / np1);
            uint32_t c = (uint32_t)(h - (size_t)r * np1);
            if (r == c) {
                if (r == (uint32_t)n) val = 1.f;
                else {
                    NodeVals nv = node_vals(lower[r], upper[r], alphas[r]);
                    val = mat ? nv.diag_up : nv.diag_low;
                }
            } else if (mat && r == (uint32_t)n) {
                val = node_vals(lower[c], upper[c], alphas[c]).bias_up;
            }
        }
        out[e] = val;
    }
}

extern "C" void kernel_launch(void* const* d_in, const int* in_sizes, int n_in,
                              void* d_out, int out_size, void* d_ws, size_t ws_size,
                              hipStream_t stream) {
    const float* lower  = (const float*)d_in[0];
    const float* upper  = (const float*)d_in[1];
    const float* alphas = (const float*)d_in[2];
    float* out = (float*)d_out;
    const int n = in_sizes[0];

    if (n == 8192) {
        // Flat one-shot grid, fill-kernel style: C4 = 33,566,720 chunks
        // = 131,120 blocks x 256 threads exactly (no bounds check).
        constexpr uint32_t C4 = (2u * 8192u + 2u * 8193u * 8193u) / 4u;
        static_assert(C4 % 256u == 0, "exact cover");
        fused_fill_flat<8193><<<C4 / 256u, 256, 0, stream>>>(lower, upper, alphas, out);
    } else {
        generic_fill<<<2048, 256, 0, stream>>>(lower, upper, alphas, out, n);
    }
}